// Round 1
// baseline (75.356 us; speedup 1.0000x reference)
//
#include <hip/hip_runtime.h>
#include <math.h>

#define DD 64

// Fast tanh via v_exp_f32: tanh(a) = (e^{2a}-1)/(e^{2a}+1).
// |zl| <= |x| + sum|W row| <= ~6 + 8, so 2a <= ~30 -> e^30 ~ 1e13, no overflow,
// but clamp anyway for safety (v_med3-able, 2 instrs).
__device__ __forceinline__ float fast_tanh(float a) {
    a = fminf(fmaxf(a, -15.0f), 15.0f);
    float e = __expf(2.0f * a);
    return (e - 1.0f) / (e + 1.0f);
}

// One wave (64 lanes) per batch row. Lane i owns element i of the row and
// W row i in registers. z broadcast through a 256B LDS buffer each iteration.
__global__ __launch_bounds__(64, 4)
void tanh_fixed_point(const float* __restrict__ x,
                      const float* __restrict__ W,
                      float* __restrict__ out)
{
    __shared__ float zsh[DD];
    const int lane = threadIdx.x;   // 0..63
    const int b    = blockIdx.x;    // batch row

    // W row `lane` into registers (64 VGPRs). Read once; L2-cached across blocks.
    float w[DD];
#pragma unroll
    for (int j = 0; j < DD; j += 4) {
        const float4 v = *reinterpret_cast<const float4*>(W + lane * DD + j);
        w[j] = v.x; w[j + 1] = v.y; w[j + 2] = v.z; w[j + 3] = v.w;
    }

    const float xi = x[b * DD + lane];
    float z = fast_tanh(xi);        // z0 = tanh(x), same as reference

    // Picard iteration z <- tanh(z W^T + x); groups of 4, wave-uniform early exit.
    for (int grp = 0; grp < 64; ++grp) {      // max 256 iterations
        float md = 0.0f;
#pragma unroll
        for (int g = 0; g < 4; ++g) {
            zsh[lane] = z;
            __syncthreads();
            float zl = xi;
#pragma unroll
            for (int j = 0; j < DD; j += 4) {
                const float4 zv = *reinterpret_cast<const float4*>(&zsh[j]);
                zl = fmaf(w[j],     zv.x, zl);
                zl = fmaf(w[j + 1], zv.y, zl);
                zl = fmaf(w[j + 2], zv.z, zl);
                zl = fmaf(w[j + 3], zv.w, zl);
            }
            __syncthreads();        // all lanes done reading before next write
            const float zn = fast_tanh(zl);
            md = fmaxf(md, fabsf(zn - z));
            z = zn;
        }
        // wave-wide max reduce (width 64)
#pragma unroll
        for (int off = 32; off; off >>= 1)
            md = fmaxf(md, __shfl_xor(md, off));
        if (md < 1e-6f) break;      // wave-uniform branch
    }

    // Mirror reference: zero rows whose residual ||z - tanh(zW^T+x)||_2 > 1e-4.
    zsh[lane] = z;
    __syncthreads();
    float zl = xi;
#pragma unroll
    for (int j = 0; j < DD; j += 4) {
        const float4 zv = *reinterpret_cast<const float4*>(&zsh[j]);
        zl = fmaf(w[j],     zv.x, zl);
        zl = fmaf(w[j + 1], zv.y, zl);
        zl = fmaf(w[j + 2], zv.z, zl);
        zl = fmaf(w[j + 3], zv.w, zl);
    }
    const float gres = z - fast_tanh(zl);
    float s = gres * gres;
#pragma unroll
    for (int off = 32; off; off >>= 1)
        s += __shfl_xor(s, off);
    if (s > 1e-8f) z = 0.0f;        // sqrt(s) > 1e-4

    out[b * DD + lane] = z;
}

extern "C" void kernel_launch(void* const* d_in, const int* in_sizes, int n_in,
                              void* d_out, int out_size, void* d_ws, size_t ws_size,
                              hipStream_t stream)
{
    const float* x = (const float*)d_in[0];   // [B, 64] fp32
    const float* W = (const float*)d_in[1];   // [64, 64] fp32
    float* out     = (float*)d_out;           // [B, 64] fp32
    const int B = in_sizes[0] / DD;           // 4096
    tanh_fixed_point<<<B, DD, 0, stream>>>(x, W, out);
}